// Round 8
// baseline (116.544 us; speedup 1.0000x reference)
//
#include <hip/hip_runtime.h>
#include <hip/hip_bf16.h>
#include <stdint.h>

// ---- problem constants ----
#define BBATCH 4
#define NSEQ   256
#define DIN    64
#define DOUT   128
#define NBASIS 8
#define KTOT   576   // 64 base (silu) + 64*8 spline features
#define K2TOT  1152  // two KANs worth of features for the final stage
#define NSTEP  18    // 576/32
#define XST16  68    // u16 stride for bf16 X rows: 136B, 8B-aligned, 2-way-free banks

typedef __attribute__((ext_vector_type(8))) __bf16 bf16x8;
typedef __attribute__((ext_vector_type(4))) float  f32x4;

__device__ __forceinline__ float wave_sum(float v){
#pragma unroll
  for (int m = 1; m < 64; m <<= 1) v += __shfl_xor(v, m, 64);
  return v;
}

__device__ __forceinline__ float fast_tanh(float y){
  y = fminf(10.f, fmaxf(-10.f, y));
  float e = __expf(2.f * y);
  return (e - 1.f) / (e + 1.f);
}

__device__ __forceinline__ float silu_f(float x){
  return __fdividef(x, 1.f + __expf(-x));
}

__device__ __forceinline__ unsigned short f2bf(float f){
  union { float f; unsigned u; } v; v.f = f;
  unsigned r = (v.u + 0x7fffu + ((v.u >> 16) & 1u)) >> 16;
  return (unsigned short)r;
}

__device__ __forceinline__ float bf2f(unsigned short s){
  union { unsigned u; float f; } v; v.u = ((unsigned)s) << 16;
  return v.f;
}

__device__ __forceinline__ float bf2f_lo(unsigned w){
  union { unsigned u; float f; } v; v.u = w << 16;
  return v.f;
}
__device__ __forceinline__ float bf2f_hi(unsigned w){
  union { unsigned u; float f; } v; v.u = w & 0xffff0000u;
  return v.f;
}

// pack two f32 -> one u32 of 2 bf16 (round-half-up) via v_perm_b32
__device__ __forceinline__ unsigned pk2(float a, float b){
  union { float f; unsigned u; } ua, ub; ua.f = a; ub.f = b;
  return __builtin_amdgcn_perm(ub.u + 0x8000u, ua.u + 0x8000u, 0x07060302);
}

// uniform cubic B-spline: grid [-1,1] step h=0.4, extended by 3 knots each side.
__device__ __forceinline__ void spline_w(float x, int &i, float w[4]){
  float u = (x + 1.f) * 2.5f;
  int ii = (int)floorf(u);
  ii = ii < 0 ? 0 : (ii > 5 ? 5 : ii);
  float t = u - (float)ii;
  float t2 = t * t, t3 = t2 * t;
  float it = 1.f - t;
  w[0] = it * it * it * (1.f/6.f);
  w[1] = (3.f*t3 - 6.f*t2 + 4.f) * (1.f/6.f);
  w[2] = (-3.f*t3 + 3.f*t2 + 3.f*t + 1.f) * (1.f/6.f);
  w[3] = t3 * (1.f/6.f);
  i = ii;
}

// full 8-slot packed spline basis row (bf16x8) for one x, in-register.
// w0..w3 land at slots i..i+3; slot 8 (i=5,k=3) falls off the shift: dropped,
// matching the reference's 8-basis truncation.
__device__ __forceinline__ bf16x8 spline_pack(float x){
  float u = (x + 1.f) * 2.5f;
  int ii = (int)floorf(u);
  ii = ii < 0 ? 0 : (ii > 5 ? 5 : ii);
  float t = u - (float)ii;
  float t2 = t * t, t3 = t2 * t;
  float it = 1.f - t;
  float w0 = it * it * it * (1.f/6.f);
  float w1 = (3.f*t3 - 6.f*t2 + 4.f) * (1.f/6.f);
  float w2 = (-3.f*t3 + 3.f*t2 + 3.f*t + 1.f) * (1.f/6.f);
  float w3 = t3 * (1.f/6.f);
  unsigned long long W = ((unsigned long long)pk2(w2, w3) << 32) | (unsigned long long)pk2(w0, w1);
  int s16 = ii << 4;
  unsigned long long shl_lo = W << (s16 & 63);
  unsigned long long shr    = W >> ((64 - s16) & 63);
  unsigned long long shl_hi = W << ((s16 - 64) & 63);
  bool ge4 = ii >= 4;
  unsigned long long lo = ge4 ? 0ull : shl_lo;
  unsigned long long hi = ge4 ? shl_hi : (ii == 0 ? 0ull : shr);
  union { unsigned long long q[2]; bf16x8 v8; } r;
  r.q[0] = lo; r.q[1] = hi;
  return r.v8;
}

// ---------- kernel A: fused prep (rows + S + wm + S2) ----------
__global__ void k_prep_all(const float* __restrict__ h,
                           const float* __restrict__ g_in, const float* __restrict__ b_in,
                           const float* __restrict__ ka_bw, const float* __restrict__ ka_sw,
                           const float* __restrict__ ka_c,  const float* __restrict__ W_att,
                           const float* __restrict__ kp_bw, const float* __restrict__ kp_sw,
                           const float* __restrict__ kp_c,
                           const float* __restrict__ kd_bw, const float* __restrict__ kd_sw,
                           const float* __restrict__ kd_c,
                           float* __restrict__ h_ln, float* __restrict__ hn,
                           unsigned short* __restrict__ S_t, float* __restrict__ wm,
                           unsigned short* __restrict__ S2){
  int blk = blockIdx.x, tid = threadIdx.x;
  if (blk < 256){                       // LN(h) + unit-norm: 4 rows/block
    int row = blk*4 + (tid >> 6);
    int d   = tid & 63;
    float x = h[row*DIN + d];
    float mean = wave_sum(x) * (1.f/64.f);
    float xm = x - mean;
    float var = wave_sum(xm*xm) * (1.f/64.f);
    float hl = xm * rsqrtf(var + 1e-5f) * g_in[d] + b_in[d];
    h_ln[row*DIN + d] = hl;
    float nrm = sqrtf(wave_sum(hl*hl));
    nrm = fmaxf(nrm, 1e-12f);
    hn[row*DIN + d] = hl / nrm;
  } else if (blk < 320){                // S_t[o][k]
    int o = blk - 256;
    for (int k = tid; k < KTOT; k += 256){
      float v;
      if (k < 64){
        v = ka_bw[o*64 + k];
      } else {
        int km = k - 64, dd = km >> 3, j = km & 7;
        float c = ka_c[(o*64 + dd)*8 + j];
        c = fminf(5.f, fmaxf(-5.f, c));
        v = c * ka_sw[o*64 + dd];
      }
      S_t[o*KTOT + k] = f2bf(v);
    }
  } else if (blk == 320){               // wm
    if (tid < 64){
      float s = 0.f;
      for (int k = 0; k < 256; ++k) s += W_att[tid*256 + k];
      wm[tid] = s * (1.f/256.f);
    }
  } else {                              // S2[o][kk] row-major
    int o = blk - 321;
    for (int kk = tid; kk < K2TOT; kk += 256){
      const float* bw; const float* sw; const float* cc;
      int k = kk;
      if (kk < KTOT){ bw = kp_bw; sw = kp_sw; cc = kp_c; }
      else          { bw = kd_bw; sw = kd_sw; cc = kd_c; k = kk - KTOT; }
      float v;
      if (k < 64){
        v = bw[o*64 + k];
      } else {
        int km = k - 64, d = km >> 3, j = km & 7;
        float c = cc[(o*64 + d)*8 + j];
        c = fminf(5.f, fmaxf(-5.f, c));
        v = c * sw[o*64 + d];
      }
      S2[o*K2TOT + kk] = f2bf(v);
    }
  }
}

// ---------- kernel B: scores[b,n,m] — symmetric, zero-barrier, pipelined B ----------
// Block (b,n), 8 waves; wave w (m-strip [32w,32w+32)) active iff w >= n>>5.
// Everything wave-private; no __syncthreads anywhere. B fragments are
// software-pipelined from global through a 3-slot register rotation
// (full unroll -> static indices -> registers; consume-to-load distance
// = 2 K-steps ~ 450 cy, covers L2 latency). R7's serial load->wait->MFMA
// chain (VGPR=56, no pipeline room) was the 64% stall.
__launch_bounds__(512, 4)
__global__ void k_scores(const float* __restrict__ hn,
                         const float* __restrict__ ln_p_g, const float* __restrict__ ln_p_b,
                         const unsigned short* __restrict__ S_t,
                         const float* __restrict__ wm,
                         float* __restrict__ scores){
  __shared__ unsigned short Xs[NSEQ * XST16];   // 256*68*2 = 34816 B -> 4 blocks/CU

  int idx  = blockIdx.x;
  int bb   = idx & 3;            // heavy (small n) blocks dispatched first
  int n    = idx >> 2;

  int tid  = threadIdx.x;
  int lane = tid & 63, wave = tid >> 6;   // 8 waves
  int m0   = wave * 32;
  if (wave < (n >> 5)) return;   // inactive waves exit immediately (no barriers below)

  // ---- issue B prefetch for K-steps 0,1 before phase 1 (hidden under LN) ----
  int colr = lane & 15, grp = lane >> 4;
  const unsigned short* bp0 = S_t + colr*KTOT;
  bf16x8 bq[3][4];
#define LOADB(slot, s) do{ const int kw_ = (s)*32 + grp*8;                      \
    bq[slot][0] = *(const bf16x8*)(bp0 + 0*16*KTOT + kw_);                      \
    bq[slot][1] = *(const bf16x8*)(bp0 + 1*16*KTOT + kw_);                      \
    bq[slot][2] = *(const bf16x8*)(bp0 + 2*16*KTOT + kw_);                      \
    bq[slot][3] = *(const bf16x8*)(bp0 + 3*16*KTOT + kw_); }while(0)
  LOADB(0, 0);
  LOADB(1, 1);

  // ---- phase 1: per-thread LN + tanh -> bf16 LDS (wave-private rows) ----
  {
    int r = lane >> 1, h = lane & 1;
    const float* xp = hn + (bb*NSEQ + m0 + r)*DIN + h*32;
    const float* np = hn + (bb*NSEQ + n)*DIN + h*32;
    float s1 = 0.f, s2 = 0.f;
#pragma unroll
    for (int i = 0; i < 8; ++i){
      float4 x4 = *(const float4*)(xp + i*4);
      float4 n4 = *(const float4*)(np + i*4);
      float p0 = x4.x*n4.x, p1 = x4.y*n4.y, p2 = x4.z*n4.z, p3 = x4.w*n4.w;
      s1 += (p0+p1) + (p2+p3);
      s2 = fmaf(p0,p0, fmaf(p1,p1, fmaf(p2,p2, fmaf(p3,p3, s2))));
    }
    s1 += __shfl_xor(s1, 1, 64);
    s2 += __shfl_xor(s2, 1, 64);
    float mean = s1 * (1.f/64.f);
    float var  = fmaxf(s2 * (1.f/64.f) - mean*mean, 0.f);
    float inv  = rsqrtf(var + 1e-5f);
    const float* gp = ln_p_g + h*32;
    const float* bp = ln_p_b + h*32;
    unsigned short* dst = Xs + (m0 + r)*XST16 + h*32;
#pragma unroll
    for (int i = 0; i < 8; ++i){
      float4 x4 = *(const float4*)(xp + i*4);
      float4 n4 = *(const float4*)(np + i*4);
      float4 g4 = *(const float4*)(gp + i*4);
      float4 b4 = *(const float4*)(bp + i*4);
      float t0 = fast_tanh((x4.x*n4.x - mean)*inv*g4.x + b4.x);
      float t1 = fast_tanh((x4.y*n4.y - mean)*inv*g4.y + b4.y);
      float t2 = fast_tanh((x4.z*n4.z - mean)*inv*g4.z + b4.z);
      float t3 = fast_tanh((x4.w*n4.w - mean)*inv*g4.w + b4.w);
      uint2 pk = { pk2(t0, t1), pk2(t2, t3) };
      *(uint2*)(dst + i*4) = pk;
    }
  }
  // same-wave LDS write->read: ordered by lgkmcnt, no __syncthreads needed.

  // ---- phase 2: MFMA K-loop, 3-slot pipelined B ----
  const unsigned short* rowA = Xs + (m0 + colr)*XST16;
  const unsigned short* rowB = Xs + (m0 + 16 + colr)*XST16;

  f32x4 acc[2][4];
#pragma unroll
  for (int a = 0; a < 2; ++a)
#pragma unroll
    for (int c = 0; c < 4; ++c){ f32x4 z = {0.f,0.f,0.f,0.f}; acc[a][c] = z; }

#pragma unroll
  for (int s = 0; s < NSTEP; ++s){
    if (s + 2 < NSTEP) LOADB((s+2)%3, s+2);   // static: s compile-time (full unroll)
    bf16x8 a0, a1;
    if (s < 2){
      // silu steps (k = 0..63): lane's 8 k-slots = 8 dims
      int kw = s*32 + grp*8;
      union { unsigned u[4]; bf16x8 v8; } A0, A1;
      uint2 wa0 = *(const uint2*)(rowA + kw), wa1 = *(const uint2*)(rowA + kw + 4);
      uint2 wb0 = *(const uint2*)(rowB + kw), wb1 = *(const uint2*)(rowB + kw + 4);
      A0.u[0] = pk2(silu_f(bf2f_lo(wa0.x)), silu_f(bf2f_hi(wa0.x)));
      A0.u[1] = pk2(silu_f(bf2f_lo(wa0.y)), silu_f(bf2f_hi(wa0.y)));
      A0.u[2] = pk2(silu_f(bf2f_lo(wa1.x)), silu_f(bf2f_hi(wa1.x)));
      A0.u[3] = pk2(silu_f(bf2f_lo(wa1.y)), silu_f(bf2f_hi(wa1.y)));
      A1.u[0] = pk2(silu_f(bf2f_lo(wb0.x)), silu_f(bf2f_hi(wb0.x)));
      A1.u[1] = pk2(silu_f(bf2f_lo(wb0.y)), silu_f(bf2f_hi(wb0.y)));
      A1.u[2] = pk2(silu_f(bf2f_lo(wb1.x)), silu_f(bf2f_hi(wb1.x)));
      A1.u[3] = pk2(silu_f(bf2f_lo(wb1.y)), silu_f(bf2f_hi(wb1.y)));
      a0 = A0.v8; a1 = A1.v8;
    } else {
      // spline steps (k = 64..575): lane's 8 k-slots = one dim's 8 bases
      int d = (s - 2)*4 + grp;
      a0 = spline_pack(bf2f(rowA[d]));
      a1 = spline_pack(bf2f(rowB[d]));
    }
#pragma unroll
    for (int nt = 0; nt < 4; ++nt){
      acc[0][nt] = __builtin_amdgcn_mfma_f32_16x16x32_bf16(a0, bq[s%3][nt], acc[0][nt], 0, 0, 0);
      acc[1][nt] = __builtin_amdgcn_mfma_f32_16x16x32_bf16(a1, bq[s%3][nt], acc[1][nt], 0, 0, 0);
    }
  }
#undef LOADB

  // ---- epilogue: score[m] = sum_o tanh(out[m][o]) * wm[o]; direct + transpose ----
  float wmv[4];
#pragma unroll
  for (int nt = 0; nt < 4; ++nt) wmv[nt] = wm[nt*16 + colr];

#pragma unroll
  for (int a = 0; a < 2; ++a){
    float sacc[4] = {0.f,0.f,0.f,0.f};
#pragma unroll
    for (int nt = 0; nt < 4; ++nt){
#pragma unroll
      for (int r = 0; r < 4; ++r)
        sacc[r] += fast_tanh(acc[a][nt][r]) * wmv[nt];
    }
#pragma unroll
    for (int off = 1; off < 16; off <<= 1){
#pragma unroll
      for (int r = 0; r < 4; ++r) sacc[r] += __shfl_xor(sacc[r], off, 64);
    }
    if (colr == 0){
      int mb   = m0 + a*16 + grp*4;
      int base = (bb*NSEQ + n)*NSEQ + mb;
      float4 v = { sacc[0], sacc[1], sacc[2], sacc[3] };
      *(float4*)&scores[base] = v;
      int tb = bb*NSEQ*NSEQ + n;
#pragma unroll
      for (int r = 0; r < 4; ++r)
        scores[tb + (mb + r)*NSEQ] = sacc[r];
    }
  }
}

// ---------- kernel C: softmax + h_att + final KANs + BN, fused ----------
__launch_bounds__(256, 8)
__global__ void k_smf(const float* __restrict__ scores,
                      const float* __restrict__ h_ln,
                      const unsigned short* __restrict__ S2,
                      const float* __restrict__ bn_g, const float* __restrict__ bn_b,
                      const float* __restrict__ bn_mean, const float* __restrict__ bn_var,
                      float* __restrict__ out){
  __shared__ float att[256];
  __shared__ float redm[4], reds[4];
  __shared__ float part[4][64];
  __shared__ float hatt[64];
  __shared__ float feat[K2TOT];
  __shared__ float pout[DOUT];
  int row = blockIdx.x;            // b*256+n
  int tid = threadIdx.x, lane = tid & 63, wave = tid >> 6;

  // softmax over m
  float sc = scores[row*NSEQ + tid] * 0.125f;
  float mx = sc;
#pragma unroll
  for (int off = 1; off < 64; off <<= 1) mx = fmaxf(mx, __shfl_xor(mx, off, 64));
  if (lane == 0) redm[wave] = mx;
  __syncthreads();
  mx = fmaxf(fmaxf(redm[0], redm[1]), fmaxf(redm[2], redm[3]));
  float e = __expf(sc - mx);
  float s = wave_sum(e);
  if (lane == 0) reds[wave] = s;
  __syncthreads();
  float tot = reds[0] + reds[1] + reds[2] + reds[3];
  att[tid] = e / tot;
  __syncthreads();

  // h_att = attn @ h_ln
  int d = lane, q = wave;
  int hb = row & ~255;             // b*256
  float a2 = 0.f;
  for (int m = q*64; m < q*64 + 64; ++m)
    a2 += att[m] * h_ln[(hb + m)*DIN + d];
  part[q][d] = a2;
  __syncthreads();
  if (tid < 64)
    hatt[tid] = part[0][tid] + part[1][tid] + part[2][tid] + part[3][tid];
  __syncthreads();

  // feature build: feat[0:576) from tanh(h_att), feat[576:1152) from tanh(h_ln)
  if (tid < 128){
    int src = tid >> 6, dd = tid & 63;
    float x = src ? h_ln[row*DIN + dd] : hatt[dd];
    x = fast_tanh(x);
    int base = src * KTOT;
    feat[base + dd] = silu_f(x);
    int fb = base + 64 + dd*8;
#pragma unroll
    for (int j = 0; j < 8; ++j) feat[fb + j] = 0.f;
    int i; float w[4];
    spline_w(x, i, w);
#pragma unroll
    for (int k = 0; k < 4; ++k){
      int j = i + k;
      if (j < 8) feat[fb + j] = w[k];
    }
  }
  __syncthreads();

  // dot: thread (o = tid&127, half = tid>>7) over 576 k
  int o = tid & 127, half = tid >> 7;
  const unsigned short* sp = S2 + o*K2TOT + half*KTOT;
  const float* fp = feat + half*KTOT;
  float acc = 0.f;
#pragma unroll 4
  for (int j = 0; j < KTOT/8; ++j){
    uint4  w  = *(const uint4*)(sp + j*8);
    float4 f0 = *(const float4*)(fp + j*8);
    float4 f1 = *(const float4*)(fp + j*8 + 4);
    acc = fmaf(f0.x, bf2f_lo(w.x), acc);
    acc = fmaf(f0.y, bf2f_hi(w.x), acc);
    acc = fmaf(f0.z, bf2f_lo(w.y), acc);
    acc = fmaf(f0.w, bf2f_hi(w.y), acc);
    acc = fmaf(f1.x, bf2f_lo(w.z), acc);
    acc = fmaf(f1.y, bf2f_hi(w.z), acc);
    acc = fmaf(f1.z, bf2f_lo(w.w), acc);
    acc = fmaf(f1.w, bf2f_hi(w.w), acc);
  }
  if (half) pout[o] = acc;
  __syncthreads();
  if (tid < 128){
    float a = acc + pout[tid];
    float r = (a - bn_mean[tid]) * rsqrtf(bn_var[tid] + 1e-5f) * bn_g[tid] + bn_b[tid];
    out[row*DOUT + tid] = r;
  }
}

extern "C" void kernel_launch(void* const* d_in, const int* in_sizes, int n_in,
                              void* d_out, int out_size, void* d_ws, size_t ws_size,
                              hipStream_t stream){
  (void)in_sizes; (void)n_in; (void)out_size; (void)ws_size;
  const float* h       = (const float*)d_in[0];
  const float* ln_in_g = (const float*)d_in[1];
  const float* ln_in_b = (const float*)d_in[2];
  const float* ln_p_g  = (const float*)d_in[3];
  const float* ln_p_b  = (const float*)d_in[4];
  const float* ka_bw   = (const float*)d_in[5];
  const float* ka_sw   = (const float*)d_in[6];
  const float* ka_c    = (const float*)d_in[7];
  const float* W_att   = (const float*)d_in[8];
  const float* kp_bw   = (const float*)d_in[9];
  const float* kp_sw   = (const float*)d_in[10];
  const float* kp_c    = (const float*)d_in[11];
  const float* kd_bw   = (const float*)d_in[12];
  const float* kd_sw   = (const float*)d_in[13];
  const float* kd_c    = (const float*)d_in[14];
  const float* bn_g    = (const float*)d_in[15];
  const float* bn_b    = (const float*)d_in[16];
  const float* bn_mean = (const float*)d_in[17];
  const float* bn_var  = (const float*)d_in[18];
  float* out = (float*)d_out;

  char* ws = (char*)d_ws;
  float*          h_ln   = (float*)(ws + 0);                        // 256 KB
  float*          hn     = (float*)(ws + 262144);                   // 256 KB
  unsigned short* S_t    = (unsigned short*)(ws + 524288);          // 72 KB
  float*          wm     = (float*)(ws + 598016);                   // 256 B
  float*          scores = (float*)(ws + 598272);                   // 1 MB
  unsigned short* S2     = (unsigned short*)(ws + 1908992);         // 288 KB

  k_prep_all<<<449, 256, 0, stream>>>(h, ln_in_g, ln_in_b, ka_bw, ka_sw, ka_c, W_att,
                                      kp_bw, kp_sw, kp_c, kd_bw, kd_sw, kd_c,
                                      h_ln, hn, S_t, wm, S2);
  k_scores<<<1024, 512, 0, stream>>>(hn, ln_p_g, ln_p_b, S_t, wm, scores);
  k_smf<<<1024, 256, 0, stream>>>(scores, h_ln, S2, bn_g, bn_b, bn_mean, bn_var, out);
}

// Round 9
// 98.785 us; speedup vs baseline: 1.1798x; 1.1798x over previous
//
#include <hip/hip_runtime.h>
#include <hip/hip_bf16.h>
#include <stdint.h>

// ---- problem constants ----
#define BBATCH 4
#define NSEQ   256
#define DIN    64
#define DOUT   128
#define NBASIS 8
#define KTOT   576   // 64 base (silu) + 64*8 spline features
#define K2TOT  1152  // two KANs worth of features for the final stage
#define NSTEP  18    // 576/32
#define XST16  68    // u16 stride for bf16 X rows: 136B, 8B-aligned, 2-way-free banks

typedef __attribute__((ext_vector_type(8))) __bf16 bf16x8;
typedef __attribute__((ext_vector_type(4))) float  f32x4;

__device__ __forceinline__ float wave_sum(float v){
#pragma unroll
  for (int m = 1; m < 64; m <<= 1) v += __shfl_xor(v, m, 64);
  return v;
}

__device__ __forceinline__ float fast_tanh(float y){
  y = fminf(10.f, fmaxf(-10.f, y));
  float e = __expf(2.f * y);
  return (e - 1.f) / (e + 1.f);
}

__device__ __forceinline__ float silu_f(float x){
  return __fdividef(x, 1.f + __expf(-x));
}

__device__ __forceinline__ unsigned short f2bf(float f){
  union { float f; unsigned u; } v; v.f = f;
  unsigned r = (v.u + 0x7fffu + ((v.u >> 16) & 1u)) >> 16;
  return (unsigned short)r;
}

__device__ __forceinline__ float bf2f(unsigned short s){
  union { unsigned u; float f; } v; v.u = ((unsigned)s) << 16;
  return v.f;
}

__device__ __forceinline__ float bf2f_lo(unsigned w){
  union { unsigned u; float f; } v; v.u = w << 16;
  return v.f;
}
__device__ __forceinline__ float bf2f_hi(unsigned w){
  union { unsigned u; float f; } v; v.u = w & 0xffff0000u;
  return v.f;
}

// pack two f32 -> one u32 of 2 bf16 (round-half-up) via v_perm_b32
__device__ __forceinline__ unsigned pk2(float a, float b){
  union { float f; unsigned u; } ua, ub; ua.f = a; ub.f = b;
  return __builtin_amdgcn_perm(ub.u + 0x8000u, ua.u + 0x8000u, 0x07060302);
}

// uniform cubic B-spline: grid [-1,1] step h=0.4, extended by 3 knots each side.
__device__ __forceinline__ void spline_w(float x, int &i, float w[4]){
  float u = (x + 1.f) * 2.5f;
  int ii = (int)floorf(u);
  ii = ii < 0 ? 0 : (ii > 5 ? 5 : ii);
  float t = u - (float)ii;
  float t2 = t * t, t3 = t2 * t;
  float it = 1.f - t;
  w[0] = it * it * it * (1.f/6.f);
  w[1] = (3.f*t3 - 6.f*t2 + 4.f) * (1.f/6.f);
  w[2] = (-3.f*t3 + 3.f*t2 + 3.f*t + 1.f) * (1.f/6.f);
  w[3] = t3 * (1.f/6.f);
  i = ii;
}

// full 8-slot packed spline basis row (bf16x8) for one x, in-register.
// w0..w3 land at slots i..i+3; slot 8 (i=5,k=3) falls off the shift: dropped,
// matching the reference's 8-basis truncation.
__device__ __forceinline__ bf16x8 spline_pack(float x){
  float u = (x + 1.f) * 2.5f;
  int ii = (int)floorf(u);
  ii = ii < 0 ? 0 : (ii > 5 ? 5 : ii);
  float t = u - (float)ii;
  float t2 = t * t, t3 = t2 * t;
  float it = 1.f - t;
  float w0 = it * it * it * (1.f/6.f);
  float w1 = (3.f*t3 - 6.f*t2 + 4.f) * (1.f/6.f);
  float w2 = (-3.f*t3 + 3.f*t2 + 3.f*t + 1.f) * (1.f/6.f);
  float w3 = t3 * (1.f/6.f);
  unsigned long long W = ((unsigned long long)pk2(w2, w3) << 32) | (unsigned long long)pk2(w0, w1);
  int s16 = ii << 4;
  unsigned long long shl_lo = W << (s16 & 63);
  unsigned long long shr    = W >> ((64 - s16) & 63);
  unsigned long long shl_hi = W << ((s16 - 64) & 63);
  bool ge4 = ii >= 4;
  unsigned long long lo = ge4 ? 0ull : shl_lo;
  unsigned long long hi = ge4 ? shl_hi : (ii == 0 ? 0ull : shr);
  union { unsigned long long q[2]; bf16x8 v8; } r;
  r.q[0] = lo; r.q[1] = hi;
  return r.v8;
}

// ---------- kernel A: fused prep (rows + S + wm + S2) ----------
__global__ void k_prep_all(const float* __restrict__ h,
                           const float* __restrict__ g_in, const float* __restrict__ b_in,
                           const float* __restrict__ ka_bw, const float* __restrict__ ka_sw,
                           const float* __restrict__ ka_c,  const float* __restrict__ W_att,
                           const float* __restrict__ kp_bw, const float* __restrict__ kp_sw,
                           const float* __restrict__ kp_c,
                           const float* __restrict__ kd_bw, const float* __restrict__ kd_sw,
                           const float* __restrict__ kd_c,
                           float* __restrict__ h_ln, float* __restrict__ hn,
                           unsigned short* __restrict__ S_t, float* __restrict__ wm,
                           unsigned short* __restrict__ S2){
  int blk = blockIdx.x, tid = threadIdx.x;
  if (blk < 256){                       // LN(h) + unit-norm: 4 rows/block
    int row = blk*4 + (tid >> 6);
    int d   = tid & 63;
    float x = h[row*DIN + d];
    float mean = wave_sum(x) * (1.f/64.f);
    float xm = x - mean;
    float var = wave_sum(xm*xm) * (1.f/64.f);
    float hl = xm * rsqrtf(var + 1e-5f) * g_in[d] + b_in[d];
    h_ln[row*DIN + d] = hl;
    float nrm = sqrtf(wave_sum(hl*hl));
    nrm = fmaxf(nrm, 1e-12f);
    hn[row*DIN + d] = hl / nrm;
  } else if (blk < 320){                // S_t[o][k]
    int o = blk - 256;
    for (int k = tid; k < KTOT; k += 256){
      float v;
      if (k < 64){
        v = ka_bw[o*64 + k];
      } else {
        int km = k - 64, dd = km >> 3, j = km & 7;
        float c = ka_c[(o*64 + dd)*8 + j];
        c = fminf(5.f, fmaxf(-5.f, c));
        v = c * ka_sw[o*64 + dd];
      }
      S_t[o*KTOT + k] = f2bf(v);
    }
  } else if (blk == 320){               // wm
    if (tid < 64){
      float s = 0.f;
      for (int k = 0; k < 256; ++k) s += W_att[tid*256 + k];
      wm[tid] = s * (1.f/256.f);
    }
  } else {                              // S2[o][kk] row-major
    int o = blk - 321;
    for (int kk = tid; kk < K2TOT; kk += 256){
      const float* bw; const float* sw; const float* cc;
      int k = kk;
      if (kk < KTOT){ bw = kp_bw; sw = kp_sw; cc = kp_c; }
      else          { bw = kd_bw; sw = kd_sw; cc = kd_c; k = kk - KTOT; }
      float v;
      if (k < 64){
        v = bw[o*64 + k];
      } else {
        int km = k - 64, d = km >> 3, j = km & 7;
        float c = cc[(o*64 + d)*8 + j];
        c = fminf(5.f, fmaxf(-5.f, c));
        v = c * sw[o*64 + d];
      }
      S2[o*K2TOT + kk] = f2bf(v);
    }
  }
}

// ---------- kernel B: scores[b,n,m] — R5 structure + bf16 X (4 blocks/CU) ----------
// Block (b,n), 8 waves; wave w (m-strip [32w,32w+32)) active iff w >= n>>5.
// Phase 0: coalesced float4 staging of hn rows -> bf16 LDS (per-wave strip).
// Phase 1: LN+tanh in place (2 threads/row), LDS reads only.
// Phase 2: MFMA K-loop, B serial from global (proven structure @59us).
// Bitwise (n,m)-symmetry: n-row is bf16-rounded too, so products are the
// same f32 operand pair in both blocks (commutative). Diagonal-strip
// transpose writes skipped (direct writes cover them; no racy doubles).
__launch_bounds__(512, 4)
__global__ void k_scores(const float* __restrict__ hn,
                         const float* __restrict__ ln_p_g, const float* __restrict__ ln_p_b,
                         const unsigned short* __restrict__ S_t,
                         const float* __restrict__ wm,
                         float* __restrict__ scores){
  __shared__ unsigned short Xs[NSEQ * XST16];   // 256*68*2 = 34816 B
  __shared__ float hnn_l[64], g_l[64], b_l[64];

  int idx  = blockIdx.x;
  int bb   = idx & 3;            // heavy (small n) blocks dispatched first
  int n    = idx >> 2;
  int sn   = n >> 5;

  int tid  = threadIdx.x;
  int lane = tid & 63, wave = tid >> 6;   // 8 waves
  int m0   = wave * 32;
  bool active = (wave >= sn);

  // ---- phase 0: coalesced staging of this wave's 32 hn rows as bf16 ----
  if (active){
    const float* src = hn + (bb*NSEQ + m0)*DIN;
#pragma unroll
    for (int j = 0; j < 8; ++j){
      int f4 = j*64 + lane;                 // float4 index in wave's 2048 floats
      float4 v = *(const float4*)(src + f4*4);
      int r = f4 >> 4, c = (f4 & 15) * 4;
      uint2 pk = { pk2(v.x, v.y), pk2(v.z, v.w) };
      *(uint2*)(Xs + (m0 + r)*XST16 + c) = pk;
    }
  }
  if (wave == 7){                // wave 7 always active
    g_l[lane]   = ln_p_g[lane];
    b_l[lane]   = ln_p_b[lane];
    hnn_l[lane] = bf2f(f2bf(hn[(bb*NSEQ + n)*DIN + lane]));  // bf16-rounded: bitwise symmetry
  }
  __syncthreads();

  // ---- phase 1: per-thread LN + tanh, in place (2 threads/row, own rows) ----
  if (active){
    int r = tid >> 1, h = tid & 1;          // r in [m0, m0+32) for this wave
    unsigned short* row = Xs + r*XST16 + h*32;
    const float* hp = hnn_l + h*32;
    float s1 = 0.f, s2 = 0.f;
#pragma unroll
    for (int i = 0; i < 8; ++i){
      uint2 w = *(const uint2*)(row + i*4);
      float x0 = bf2f_lo(w.x), x1 = bf2f_hi(w.x), x2 = bf2f_lo(w.y), x3 = bf2f_hi(w.y);
      float p0 = x0*hp[i*4+0], p1 = x1*hp[i*4+1], p2 = x2*hp[i*4+2], p3 = x3*hp[i*4+3];
      s1 += (p0+p1) + (p2+p3);
      s2 = fmaf(p0,p0, fmaf(p1,p1, fmaf(p2,p2, fmaf(p3,p3, s2))));
    }
    s1 += __shfl_xor(s1, 1, 64);
    s2 += __shfl_xor(s2, 1, 64);
    float mean = s1 * (1.f/64.f);
    float var  = fmaxf(s2 * (1.f/64.f) - mean*mean, 0.f);
    float inv  = rsqrtf(var + 1e-5f);
    const float* gp = g_l + h*32;
    const float* bp = b_l + h*32;
#pragma unroll
    for (int i = 0; i < 8; ++i){
      uint2 w = *(const uint2*)(row + i*4);
      float x0 = bf2f_lo(w.x), x1 = bf2f_hi(w.x), x2 = bf2f_lo(w.y), x3 = bf2f_hi(w.y);
      float t0 = fast_tanh((x0*hp[i*4+0] - mean)*inv*gp[i*4+0] + bp[i*4+0]);
      float t1 = fast_tanh((x1*hp[i*4+1] - mean)*inv*gp[i*4+1] + bp[i*4+1]);
      float t2 = fast_tanh((x2*hp[i*4+2] - mean)*inv*gp[i*4+2] + bp[i*4+2]);
      float t3 = fast_tanh((x3*hp[i*4+3] - mean)*inv*gp[i*4+3] + bp[i*4+3]);
      uint2 pk = { pk2(t0, t1), pk2(t2, t3) };
      *(uint2*)(row + i*4) = pk;
    }
  }
  __syncthreads();
  if (!active) return;            // no barriers after this point

  // ---- phase 2: MFMA K-loop, B serial from global ----
  int colr = lane & 15, grp = lane >> 4;
  const unsigned short* rowA = Xs + (m0 + colr)*XST16;
  const unsigned short* rowB = Xs + (m0 + 16 + colr)*XST16;
  const unsigned short* bp0 = S_t + colr*KTOT;

  f32x4 acc[2][4];
#pragma unroll
  for (int a = 0; a < 2; ++a)
#pragma unroll
    for (int c = 0; c < 4; ++c){ f32x4 z = {0.f,0.f,0.f,0.f}; acc[a][c] = z; }

  // silu steps (k = 0..63): lane's 8 k-slots = 8 dims
#pragma unroll
  for (int s = 0; s < 2; ++s){
    int kw = s*32 + grp*8;
    bf16x8 bf[4];
#pragma unroll
    for (int nt = 0; nt < 4; ++nt)
      bf[nt] = *(const bf16x8*)(bp0 + nt*16*KTOT + kw);
    union { unsigned u[4]; bf16x8 v8; } a0, a1;
    uint2 wa0 = *(const uint2*)(rowA + kw), wa1 = *(const uint2*)(rowA + kw + 4);
    uint2 wb0 = *(const uint2*)(rowB + kw), wb1 = *(const uint2*)(rowB + kw + 4);
    a0.u[0] = pk2(silu_f(bf2f_lo(wa0.x)), silu_f(bf2f_hi(wa0.x)));
    a0.u[1] = pk2(silu_f(bf2f_lo(wa0.y)), silu_f(bf2f_hi(wa0.y)));
    a0.u[2] = pk2(silu_f(bf2f_lo(wa1.x)), silu_f(bf2f_hi(wa1.x)));
    a0.u[3] = pk2(silu_f(bf2f_lo(wa1.y)), silu_f(bf2f_hi(wa1.y)));
    a1.u[0] = pk2(silu_f(bf2f_lo(wb0.x)), silu_f(bf2f_hi(wb0.x)));
    a1.u[1] = pk2(silu_f(bf2f_lo(wb0.y)), silu_f(bf2f_hi(wb0.y)));
    a1.u[2] = pk2(silu_f(bf2f_lo(wb1.x)), silu_f(bf2f_hi(wb1.x)));
    a1.u[3] = pk2(silu_f(bf2f_lo(wb1.y)), silu_f(bf2f_hi(wb1.y)));
#pragma unroll
    for (int nt = 0; nt < 4; ++nt){
      acc[0][nt] = __builtin_amdgcn_mfma_f32_16x16x32_bf16(a0.v8, bf[nt], acc[0][nt], 0, 0, 0);
      acc[1][nt] = __builtin_amdgcn_mfma_f32_16x16x32_bf16(a1.v8, bf[nt], acc[1][nt], 0, 0, 0);
    }
  }

  // spline steps (k = 64..575): lane's 8 k-slots = one dim's 8 bases
#pragma unroll 4
  for (int s = 2; s < NSTEP; ++s){
    int kw = s*32 + grp*8;
    int d  = (s - 2)*4 + grp;
    bf16x8 bf[4];
#pragma unroll
    for (int nt = 0; nt < 4; ++nt)
      bf[nt] = *(const bf16x8*)(bp0 + nt*16*KTOT + kw);
    bf16x8 a0 = spline_pack(bf2f(rowA[d]));
    bf16x8 a1 = spline_pack(bf2f(rowB[d]));
#pragma unroll
    for (int nt = 0; nt < 4; ++nt){
      acc[0][nt] = __builtin_amdgcn_mfma_f32_16x16x32_bf16(a0, bf[nt], acc[0][nt], 0, 0, 0);
      acc[1][nt] = __builtin_amdgcn_mfma_f32_16x16x32_bf16(a1, bf[nt], acc[1][nt], 0, 0, 0);
    }
  }

  // ---- epilogue: score[m] = sum_o tanh(out[m][o]) * wm[o]; direct + transpose ----
  float wmv[4];
#pragma unroll
  for (int nt = 0; nt < 4; ++nt) wmv[nt] = wm[nt*16 + colr];

#pragma unroll
  for (int a = 0; a < 2; ++a){
    float sacc[4] = {0.f,0.f,0.f,0.f};
#pragma unroll
    for (int nt = 0; nt < 4; ++nt){
#pragma unroll
      for (int r = 0; r < 4; ++r)
        sacc[r] += fast_tanh(acc[a][nt][r]) * wmv[nt];
    }
#pragma unroll
    for (int off = 1; off < 16; off <<= 1){
#pragma unroll
      for (int r = 0; r < 4; ++r) sacc[r] += __shfl_xor(sacc[r], off, 64);
    }
    if (colr == 0){
      int mb   = m0 + a*16 + grp*4;
      int base = (bb*NSEQ + n)*NSEQ + mb;
      float4 v = { sacc[0], sacc[1], sacc[2], sacc[3] };
      *(float4*)&scores[base] = v;
      if (wave > sn){             // diagonal strip covered by direct writes
        int tb = bb*NSEQ*NSEQ + n;
#pragma unroll
        for (int r = 0; r < 4; ++r)
          scores[tb + (mb + r)*NSEQ] = sacc[r];
      }
    }
  }
}

// ---------- kernel C: softmax + h_att + final KANs + BN, fused ----------
__launch_bounds__(256, 8)
__global__ void k_smf(const float* __restrict__ scores,
                      const float* __restrict__ h_ln,
                      const unsigned short* __restrict__ S2,
                      const float* __restrict__ bn_g, const float* __restrict__ bn_b,
                      const float* __restrict__ bn_mean, const float* __restrict__ bn_var,
                      float* __restrict__ out){
  __shared__ float att[256];
  __shared__ float redm[4], reds[4];
  __shared__ float part[4][64];
  __shared__ float hatt[64];
  __shared__ float feat[K2TOT];
  __shared__ float pout[DOUT];
  int row = blockIdx.x;            // b*256+n
  int tid = threadIdx.x, lane = tid & 63, wave = tid >> 6;

  // softmax over m
  float sc = scores[row*NSEQ + tid] * 0.125f;
  float mx = sc;
#pragma unroll
  for (int off = 1; off < 64; off <<= 1) mx = fmaxf(mx, __shfl_xor(mx, off, 64));
  if (lane == 0) redm[wave] = mx;
  __syncthreads();
  mx = fmaxf(fmaxf(redm[0], redm[1]), fmaxf(redm[2], redm[3]));
  float e = __expf(sc - mx);
  float s = wave_sum(e);
  if (lane == 0) reds[wave] = s;
  __syncthreads();
  float tot = reds[0] + reds[1] + reds[2] + reds[3];
  att[tid] = e / tot;
  __syncthreads();

  // h_att = attn @ h_ln
  int d = lane, q = wave;
  int hb = row & ~255;             // b*256
  float a2 = 0.f;
  for (int m = q*64; m < q*64 + 64; ++m)
    a2 += att[m] * h_ln[(hb + m)*DIN + d];
  part[q][d] = a2;
  __syncthreads();
  if (tid < 64)
    hatt[tid] = part[0][tid] + part[1][tid] + part[2][tid] + part[3][tid];
  __syncthreads();

  // feature build: feat[0:576) from tanh(h_att), feat[576:1152) from tanh(h_ln)
  if (tid < 128){
    int src = tid >> 6, dd = tid & 63;
    float x = src ? h_ln[row*DIN + dd] : hatt[dd];
    x = fast_tanh(x);
    int base = src * KTOT;
    feat[base + dd] = silu_f(x);
    int fb = base + 64 + dd*8;
#pragma unroll
    for (int j = 0; j < 8; ++j) feat[fb + j] = 0.f;
    int i; float w[4];
    spline_w(x, i, w);
#pragma unroll
    for (int k = 0; k < 4; ++k){
      int j = i + k;
      if (j < 8) feat[fb + j] = w[k];
    }
  }
  __syncthreads();

  // dot: thread (o = tid&127, half = tid>>7) over 576 k
  int o = tid & 127, half = tid >> 7;
  const unsigned short* sp = S2 + o*K2TOT + half*KTOT;
  const float* fp = feat + half*KTOT;
  float acc = 0.f;
#pragma unroll 4
  for (int j = 0; j < KTOT/8; ++j){
    uint4  w  = *(const uint4*)(sp + j*8);
    float4 f0 = *(const float4*)(fp + j*8);
    float4 f1 = *(const float4*)(fp + j*8 + 4);
    acc = fmaf(f0.x, bf2f_lo(w.x), acc);
    acc = fmaf(f0.y, bf2f_hi(w.x), acc);
    acc = fmaf(f0.z, bf2f_lo(w.y), acc);
    acc = fmaf(f0.w, bf2f_hi(w.y), acc);
    acc = fmaf(f1.x, bf2f_lo(w.z), acc);
    acc = fmaf(f1.y, bf2f_hi(w.z), acc);
    acc = fmaf(f1.z, bf2f_lo(w.w), acc);
    acc = fmaf(f1.w, bf2f_hi(w.w), acc);
  }
  if (half) pout[o] = acc;
  __syncthreads();
  if (tid < 128){
    float a = acc + pout[tid];
    float r = (a - bn_mean[tid]) * rsqrtf(bn_var[tid] + 1e-5f) * bn_g[tid] + bn_b[tid];
    out[row*DOUT + tid] = r;
  }
}

extern "C" void kernel_launch(void* const* d_in, const int* in_sizes, int n_in,
                              void* d_out, int out_size, void* d_ws, size_t ws_size,
                              hipStream_t stream){
  (void)in_sizes; (void)n_in; (void)out_size; (void)ws_size;
  const float* h       = (const float*)d_in[0];
  const float* ln_in_g = (const float*)d_in[1];
  const float* ln_in_b = (const float*)d_in[2];
  const float* ln_p_g  = (const float*)d_in[3];
  const float* ln_p_b  = (const float*)d_in[4];
  const float* ka_bw   = (const float*)d_in[5];
  const float* ka_sw   = (const float*)d_in[6];
  const float* ka_c    = (const float*)d_in[7];
  const float* W_att   = (const float*)d_in[8];
  const float* kp_bw   = (const float*)d_in[9];
  const float* kp_sw   = (const float*)d_in[10];
  const float* kp_c    = (const float*)d_in[11];
  const float* kd_bw   = (const float*)d_in[12];
  const float* kd_sw   = (const float*)d_in[13];
  const float* kd_c    = (const float*)d_in[14];
  const float* bn_g    = (const float*)d_in[15];
  const float* bn_b    = (const float*)d_in[16];
  const float* bn_mean = (const float*)d_in[17];
  const float* bn_var  = (const float*)d_in[18];
  float* out = (float*)d_out;

  char* ws = (char*)d_ws;
  float*          h_ln   = (float*)(ws + 0);                        // 256 KB
  float*          hn     = (float*)(ws + 262144);                   // 256 KB
  unsigned short* S_t    = (unsigned short*)(ws + 524288);          // 72 KB
  float*          wm     = (float*)(ws + 598016);                   // 256 B
  float*          scores = (float*)(ws + 598272);                   // 1 MB
  unsigned short* S2     = (unsigned short*)(ws + 1908992);         // 288 KB

  k_prep_all<<<449, 256, 0, stream>>>(h, ln_in_g, ln_in_b, ka_bw, ka_sw, ka_c, W_att,
                                      kp_bw, kp_sw, kp_c, kd_bw, kd_sw, kd_c,
                                      h_ln, hn, S_t, wm, S2);
  k_scores<<<1024, 512, 0, stream>>>(hn, ln_p_g, ln_p_b, S_t, wm, scores);
  k_smf<<<1024, 256, 0, stream>>>(scores, h_ln, S2, bn_g, bn_b, bn_mean, bn_var, out);
}